// Round 1
// 91.308 us; speedup vs baseline: 1.0985x; 1.0985x over previous
//
#include <hip/hip_runtime.h>
#include <math.h>

// QuantumLayer, repacked: 16 complex amplitudes per lane, 4 batch elements
// per 64-lane wave (one batch element per 16-lane group).
// Amp index i (8 bits, wire w <-> bit 7-w):
//   bits 7..4 = lane&15  -> wires 0..3 are LANE wires (shfl_xor, mask 8/4/2/1)
//   bits 3..0 = k (0..15)-> wires 4..7 are LOCAL wires (register-only mixes)
//
// Round 3: algebraic folding.
//  - RY embedding + Rot layer 0 act on a PRODUCT state -> build per-wire
//    2-vectors v_w = Rot_w * RY(ang_w)|0> and construct amplitudes directly.
//  - CNOT rings are GF(2)-linear basis permutations. Ring r=1 is folded into
//    the construction (build at permuted indices: selector bits are XORs of
//    lane/slot bits). Ring r=3 is folded into measurement (Z_w on permuted
//    state = parity observable on pre-ring state; 5 distinct local masks).
//  - Only Rot layers 1,2 and ring r=2 remain gate-wise (entangled state).

namespace {

constexpr float PI_F = 3.14159265358979323846f;

struct Cx { float re, im; };

__device__ __forceinline__ float shfx(float v, int m) {
  return __shfl_xor(v, m, 64);
}

__device__ __forceinline__ Cx cmul(Cx a, Cx b) {
  Cx r;
  r.re = a.re * b.re - a.im * b.im;
  r.im = a.re * b.im + a.im * b.re;
  return r;
}

__device__ __forceinline__ Cx csel(Cx lo, Cx hi, int c) {
  Cx r;
  r.re = c ? hi.re : lo.re;
  r.im = c ? hi.im : lo.im;
  return r;
}

// new_a = u00*a + u01*b ; new_b = u10*a + u11*b   (complex)
__device__ __forceinline__ void mix2(Cx &a, Cx &b,
    float u00r, float u00i, float u01r, float u01i,
    float u10r, float u10i, float u11r, float u11i) {
  float ar = a.re, ai = a.im, br = b.re, bi = b.im;
  a.re = u00r*ar - u00i*ai + u01r*br - u01i*bi;
  a.im = u00r*ai + u00i*ar + u01r*bi + u01i*br;
  b.re = u10r*ar - u10i*ai + u11r*br - u11i*bi;
  b.im = u10r*ai + u10i*ar + u11r*bi + u11i*br;
}

// Apply 2x2 unitary on wire W. Zero-constant coefs fold after inlining.
template<int W>
__device__ __forceinline__ void apply1q(Cx s[16],
    float u00r, float u00i, float u01r, float u01i,
    float u10r, float u10i, float u11r, float u11i, int lane) {
  if constexpr (W >= 4) {                 // local bit lb = 7-W (3..0)
    constexpr int step = 1 << (7 - W);
#pragma unroll
    for (int k = 0; k < 16; ++k)
      if (!(k & step))
        mix2(s[k], s[k + step], u00r,u00i,u01r,u01i,u10r,u10i,u11r,u11i);
  } else {                                // lane bit 3-W
    constexpr int lm = 1 << (3 - W);
    const bool hi = (lane & lm) != 0;
    float cAr = hi ? u11r : u00r, cAi = hi ? u11i : u00i;  // coef of mine
    float cBr = hi ? u10r : u01r, cBi = hi ? u10i : u01i;  // coef of theirs
#pragma unroll
    for (int k = 0; k < 16; ++k) {
      float tr = shfx(s[k].re, lm), ti = shfx(s[k].im, lm);
      float mr = s[k].re, mi = s[k].im;
      s[k].re = cAr*mr - cAi*mi + cBr*tr - cBi*ti;
      s[k].im = cAr*mi + cAi*mr + cBr*ti + cBi*tr;
    }
  }
}

// PennyLane Rot = RZ(om) RY(th) RZ(phi); qw[L][W][0..2] = phi,th,om.
template<int L, int W>
__device__ __forceinline__ void rotW(Cx s[16], const float* __restrict__ qw, int lane) {
  float phi = qw[L*24 + W*3 + 0];
  float th  = qw[L*24 + W*3 + 1];
  float om  = qw[L*24 + W*3 + 2];
  float c  = __cosf(0.5f*th), sn = __sinf(0.5f*th);
  float a  = 0.5f*(phi + om), d = 0.5f*(phi - om);
  float ca = __cosf(a), sa = __sinf(a);
  float cd = __cosf(d), sd = __sinf(d);
  // u00 = c*e^{-ia}; u01 = -s*e^{+id}; u10 = s*e^{-id}; u11 = c*e^{+ia}
  apply1q<W>(s, c*ca, -c*sa, -sn*cd, -sn*sd, sn*cd, -sn*sd, c*ca, c*sa, lane);
}

__device__ __forceinline__ void swapc(Cx &a, Cx &b) { Cx t = a; a = b; b = t; }

__device__ __forceinline__ void cswap(Cx &a, Cx &b, bool c) {
  float ar = a.re, ai = a.im;
  a.re = c ? b.re : a.re;  a.im = c ? b.im : a.im;
  b.re = c ? ar : b.re;    b.im = c ? ai : b.im;
}

// CNOT(CW, TW): if bit(7-CW)==1, flip bit(7-TW).
template<int CW, int TW>
__device__ __forceinline__ void cnot(Cx s[16], int lane) {
  constexpr int pc = 7 - CW, pt = 7 - TW;
  if constexpr (pc >= 4 && pt >= 4) {
    // both bits in lane nibble
    constexpr int lmC = 1 << (pc - 4), lmT = 1 << (pt - 4);
    const bool ctl = (lane & lmC) != 0;
#pragma unroll
    for (int k = 0; k < 16; ++k) {
      float tr = shfx(s[k].re, lmT), ti = shfx(s[k].im, lmT);
      s[k].re = ctl ? tr : s[k].re;
      s[k].im = ctl ? ti : s[k].im;
    }
  } else if constexpr (pc >= 4) {
    // lane control, local target: conditional local swap
    constexpr int lmC = 1 << (pc - 4), step = 1 << pt;
    const bool ctl = (lane & lmC) != 0;
#pragma unroll
    for (int k = 0; k < 16; ++k)
      if (!(k & step)) cswap(s[k], s[k + step], ctl);
  } else if constexpr (pt >= 4) {
    // local control, lane target: amps with ctl bit set swap with partner lane
    constexpr int lmT = 1 << (pt - 4), cb = 1 << pc;
#pragma unroll
    for (int k = 0; k < 16; ++k)
      if (k & cb) {
        s[k].re = shfx(s[k].re, lmT);
        s[k].im = shfx(s[k].im, lmT);
      }
  } else {
    // both local: pure register renames
    constexpr int cb = 1 << pc, tb = 1 << pt;
#pragma unroll
    for (int k = 0; k < 16; ++k)
      if ((k & cb) && !(k & tb)) swapc(s[k], s[k + tb]);
  }
}

template<int L>
__device__ __forceinline__ void rotLayer(Cx s[16], const float* __restrict__ qw, int lane) {
  rotW<L,0>(s, qw, lane); rotW<L,1>(s, qw, lane);
  rotW<L,2>(s, qw, lane); rotW<L,3>(s, qw, lane);
  rotW<L,4>(s, qw, lane); rotW<L,5>(s, qw, lane);
  rotW<L,6>(s, qw, lane); rotW<L,7>(s, qw, lane);
}

__global__ __launch_bounds__(256) void quantum_layer_kernel(
    const float* __restrict__ x, const float* __restrict__ Wm,
    const float* __restrict__ bvec, const float* __restrict__ scale,
    const float* __restrict__ bias, const float* __restrict__ qw,
    float* __restrict__ out) {
  const int tid  = threadIdx.x;
  const int lane = tid & 63;
  const int ll   = lane & 15;                    // lane within 16-lane group
  const int b    = blockIdx.x * 16 + (tid >> 4); // batch element

  // ---- Phase 1: proj = x@W.T + b ; angles = sigmoid(proj*scale+bias)*pi ----
  // 16 lanes per batch row; lane ll covers cols 4*(j*16+ll), j=0..7.
  const float4* x4 = (const float4*)(x + (size_t)b * 512);
  float4 xs[8];
#pragma unroll
  for (int j = 0; j < 8; ++j) xs[j] = x4[j * 16 + ll];
  const float4* W4 = (const float4*)Wm;
  float ang[8];
#pragma unroll
  for (int q = 0; q < 8; ++q) {
    float acc = 0.f;
#pragma unroll
    for (int j = 0; j < 8; ++j) {
      float4 w = W4[q * 128 + j * 16 + ll];
      acc += xs[j].x*w.x + xs[j].y*w.y + xs[j].z*w.z + xs[j].w*w.w;
    }
    ang[q] = acc;
  }
#pragma unroll
  for (int off = 8; off >= 1; off >>= 1)
#pragma unroll
    for (int q = 0; q < 8; ++q)
      ang[q] += shfx(ang[q], off);
#pragma unroll
  for (int q = 0; q < 8; ++q) {
    float t = (ang[q] + bvec[q]) * scale[q] + bias[q];
    ang[q] = PI_F / (1.f + __expf(-t));   // sigmoid(t)*pi
  }

  // ---- Phase 2a: per-wire 2-vectors v_w = Rot_w(layer 0) * RY(ang_w)|0> ----
  // RY|0> = (cos h, sin h), h = ang/2 (real).
  // Rot: u00=(c*ca,-c*sa) u01=(-s*cd,-s*sd) u10=(s*cd,-s*sd) u11=(c*ca,c*sa)
  Cx v[8][2];
#pragma unroll
  for (int w = 0; w < 8; ++w) {
    float h  = 0.5f * ang[w];
    float c0 = __cosf(h), s0 = __sinf(h);
    float phi = qw[w*3 + 0], th = qw[w*3 + 1], om = qw[w*3 + 2];  // layer 0
    float cth = __cosf(0.5f*th), sth = __sinf(0.5f*th);
    float a  = 0.5f*(phi + om), d = 0.5f*(phi - om);
    float ca = __cosf(a), sa = __sinf(a);
    float cd = __cosf(d), sd = __sinf(d);
    v[w][0].re =  cth*ca*c0 - sth*cd*s0;
    v[w][0].im = -cth*sa*c0 - sth*sd*s0;
    v[w][1].re =  sth*cd*c0 + cth*ca*s0;
    v[w][1].im = -sth*sd*c0 + cth*sa*s0;
  }

  // ---- Phase 2b: build state directly at post-ring-r=1 indices. ----
  // Ring r=1 (cnot<0,1>..<7,0>) is a GF(2)-linear index permutation; inverting
  // it gives per-wire selector bits as XORs of the target index bits:
  //   j bits 7..4 = ll bits b3..b0, j bits 3..0 = k bits kb3..kb0
  //   e0=kb0^b3  e1=b2^kb0^b3  e2=b1^b2  e3=b0^b1
  //   e4=kb3^b0  e5=kb2^kb3    e6=kb1^kb2 e7=kb0^kb1
  // s[j] = prod_w v[w][e_w].
  const int b0 = ll & 1, b1 = (ll >> 1) & 1, b2 = (ll >> 2) & 1, b3 = (ll >> 3) & 1;

  Cx A[2];   // A[t] = v0[t^b3] * v1[t^b3^b2]   (t = kb0)
  A[0] = cmul(csel(v[0][0], v[0][1], b3),     csel(v[1][0], v[1][1], b3 ^ b2));
  A[1] = cmul(csel(v[0][0], v[0][1], b3 ^ 1), csel(v[1][0], v[1][1], b3 ^ b2 ^ 1));
  Cx Lf = cmul(csel(v[2][0], v[2][1], b1 ^ b2), csel(v[3][0], v[3][1], b0 ^ b1));
  Cx AL[2] = { cmul(A[0], Lf), cmul(A[1], Lf) };
  Cx B[2];   // B[t] = v4[t^b0]                 (t = kb3)
  B[0] = csel(v[4][0], v[4][1], b0);
  B[1] = csel(v[4][0], v[4][1], b0 ^ 1);

  Cx G01[2][2], G23[2][2];
#pragma unroll
  for (int t0 = 0; t0 < 2; ++t0)
#pragma unroll
    for (int t1 = 0; t1 < 2; ++t1)
      G01[t0][t1] = cmul(AL[t0], v[7][t0 ^ t1]);   // * v7[kb0^kb1]
#pragma unroll
  for (int t2 = 0; t2 < 2; ++t2)
#pragma unroll
    for (int t3 = 0; t3 < 2; ++t3)
      G23[t2][t3] = cmul(B[t3], v[5][t2 ^ t3]);    // * v5[kb2^kb3]

  Cx s[16];
#pragma unroll
  for (int k = 0; k < 16; ++k) {
    const int kb0 = k & 1, kb1 = (k >> 1) & 1, kb2 = (k >> 2) & 1, kb3 = (k >> 3) & 1;
    s[k] = cmul(cmul(G01[kb0][kb1], v[6][kb1 ^ kb2]), G23[kb2][kb3]);
  }

  // ---- Phase 2c: remaining entangled layers (gate-wise) ----
  rotLayer<1>(s, qw, lane);   // then ring r=2
  cnot<0,2>(s, lane); cnot<1,3>(s, lane); cnot<2,4>(s, lane); cnot<3,5>(s, lane);
  cnot<4,6>(s, lane); cnot<5,7>(s, lane); cnot<6,0>(s, lane); cnot<7,1>(s, lane);

  rotLayer<2>(s, qw, lane);   // ring r=3 folded into measurement below

  // ---- Phase 3: <Z_w> with ring r=3 folded as parity observables. ----
  // Final-index bit for z_w (pos 7-w) maps back to pre-ring bits:
  //   z0: kb2 ^ b1^b3      z1: kb1 ^ b0^b2^b3   z2: kb0^kb3 ^ b1^b2
  //   z3:       b0^b3      z4: kb3 ^ b2         z5: kb2 ^ b1
  //   z6: kb1 ^ b0^b3      z7: kb0^kb3 ^ b2
  float p[16];
#pragma unroll
  for (int k = 0; k < 16; ++k) p[k] = s[k].re*s[k].re + s[k].im*s[k].im;

  // Signed reductions over k for the 5 distinct local masks {0,2,4,8,9}.
  float sA[8], dA[8];
#pragma unroll
  for (int m = 0; m < 8; ++m) {            // kb0
    sA[m] = p[2*m] + p[2*m+1];
    dA[m] = p[2*m] - p[2*m+1];
  }
  float sB[4], dB[4], nB[4];
#pragma unroll
  for (int m = 0; m < 4; ++m) {            // kb1
    sB[m] = sA[2*m] + sA[2*m+1];
    dB[m] = sA[2*m] - sA[2*m+1];           // sign kb1
    nB[m] = dA[2*m] + dA[2*m+1];           // kb0 path, kb1 unsigned
  }
  float sC[2], cC[2], tC[2], nC[2];
#pragma unroll
  for (int m = 0; m < 2; ++m) {            // kb2
    sC[m] = sB[2*m] + sB[2*m+1];
    cC[m] = sB[2*m] - sB[2*m+1];           // sign kb2
    tC[m] = dB[2*m] + dB[2*m+1];
    nC[m] = nB[2*m] + nB[2*m+1];
  }
  float R0 = sC[0] + sC[1];                // mask 0
  float R8 = sC[0] - sC[1];                // mask 8  (kb3)
  float R4 = cC[0] + cC[1];                // mask 4  (kb2)
  float R2 = tC[0] + tC[1];                // mask 2  (kb1)
  float R9 = nC[0] - nC[1];                // mask 9  (kb0^kb3)

  const int g02 = b1 ^ b3, g1 = b0 ^ b2 ^ b3, g2 = b1 ^ b2, g36 = b0 ^ b3;
  float z[8];
  z[0] = g02 ? -R4 : R4;
  z[1] = g1  ? -R2 : R2;
  z[2] = g2  ? -R9 : R9;
  z[3] = g36 ? -R0 : R0;
  z[4] = b2  ? -R8 : R8;
  z[5] = b1  ? -R4 : R4;
  z[6] = g36 ? -R2 : R2;
  z[7] = b2  ? -R9 : R9;

#pragma unroll
  for (int off = 8; off >= 1; off >>= 1)
#pragma unroll
    for (int w = 0; w < 8; ++w)
      z[w] += shfx(z[w], off);

  if (ll == 0) {
    float4* op = (float4*)(out + (size_t)b * 8);
    op[0] = make_float4(z[0], z[1], z[2], z[3]);
    op[1] = make_float4(z[4], z[5], z[6], z[7]);
  }
}

}  // namespace

extern "C" void kernel_launch(void* const* d_in, const int* in_sizes, int n_in,
                              void* d_out, int out_size, void* d_ws, size_t ws_size,
                              hipStream_t stream) {
  const float* x     = (const float*)d_in[0];  // (8192, 512)
  const float* Wm    = (const float*)d_in[1];  // (8, 512)
  const float* bvec  = (const float*)d_in[2];  // (8,)
  const float* scale = (const float*)d_in[3];  // (8,)
  const float* bias  = (const float*)d_in[4];  // (8,)
  const float* qw    = (const float*)d_in[5];  // (3, 8, 3)
  float* out = (float*)d_out;                  // (8192, 8)

  constexpr int BATCH = 8192;
  // 256 threads = 4 waves = 16 batch elements per block
  dim3 grid(BATCH / 16), block(256);
  hipLaunchKernelGGL(quantum_layer_kernel, grid, block, 0, stream,
                     x, Wm, bvec, scale, bias, qw, out);
}